// Round 1
// baseline (1065.418 us; speedup 1.0000x reference)
//
#include <hip/hip_runtime.h>
#include <math.h>

#define HP 265
#define NPIX 70225        // 265*265
#define NB 8
#define BW 32
#define NKC 13            // computed forward rows 0..12 (rest via conjugacy)
#define TWO_PI 6.28318530717958647692f

// ws layout (float offsets)
#define OFF_X     0            // [8][32][265][265]            17,977,600
#define OFF_UPART 17977600     // [256][4][13][265] cplx        7,055,360
#define OFF_U     25032960     // [256][13][265] cplx           1,764,480
#define OFF_XFT   26797440     // [8][32][24][12] cplx            147,456
#define OFF_G     26944896     // [8][32][24][12] cplx            147,456
#define OFF_A     27092352     // [8][265][32][12] cplx          1,628,160
#define OFF_TF    28720512     // [265][13][2]                      6,890
// total 28,727,402 floats = 114.9 MB

__device__ __forceinline__ float gelu_f(float v){
  return 0.5f * v * (1.0f + erff(v * 0.70710678118654752f));
}

// Forward twiddle table: Tf[h][k] = exp(-2*pi*i*(h*k mod 265)/265)
__global__ void k_init_tw(float* __restrict__ Tf){
  int idx = blockIdx.x*256 + threadIdx.x;
  if (idx >= HP*NKC) return;
  int h = idx / NKC, k = idx % NKC;
  int t = (h*k) % HP;
  float ang = -TWO_PI * (float)t / (float)HP;
  float s, c; sincosf(ang, &s, &c);
  Tf[idx*2+0] = c;
  Tf[idx*2+1] = s;
}

// fc0: x[b,d,h,w] = sum_c x_en[b,c,h,w]*W[c,d] + B[d]; zero pad h,w in [256,265)
__global__ void k_fc0(const float* __restrict__ xen, const float* __restrict__ w0,
                      const float* __restrict__ b0, float* __restrict__ xb){
  int idx = blockIdx.x*256 + threadIdx.x;       // [b][d][h][w] over 265x265
  int w = idx % HP; int t = idx / HP; int h = t % HP; t /= HP;
  int d = t % BW; int b = t / BW;
  float v = 0.f;
  if (h < 256 && w < 256){
    const float* xp = xen + (((size_t)b*3)*256 + h)*256 + w;
    v = b0[d] + xp[0]*w0[d] + xp[65536]*w0[32+d] + xp[131072]*w0[64+d];
  }
  xb[idx] = v;
}

// copy x_en -> out section 3, and x_de (::4,::4) -> out section 1
__global__ void k_copy(const float* __restrict__ xen, float* __restrict__ out){
  int idx = blockIdx.x*256 + threadIdx.x;
  if (idx >= 1572864) return;
  float v = xen[idx];
  out[1769472 + idx] = v;
  int w = idx & 255, h = (idx >> 8) & 255, bc = idx >> 16;
  if (((h|w)&3) == 0)
    out[98304 + bc*4096 + ((h>>2)<<6) + (w>>2)] = v;
}

// Row DFT over h (negative exponent), 13 modes, split h into 4 chunks over grid.x
__global__ __launch_bounds__(320) void k_dft_h(const float* __restrict__ xb,
                                               const float* __restrict__ Tf,
                                               float2* __restrict__ Upart){
  int w  = threadIdx.x;
  int hq = blockIdx.x;     // 0..3
  int bi = blockIdx.y;     // 0..255
  if (w >= HP) return;
  int h0 = hq*67;
  int h1 = (h0 + 67 < HP) ? h0 + 67 : HP;
  float ur[NKC], ui[NKC];
  #pragma unroll
  for (int k = 0; k < NKC; ++k){ ur[k] = 0.f; ui[k] = 0.f; }
  const float* xp = xb + (size_t)bi*NPIX + w;
  for (int h = h0; h < h1; ++h){
    float v = xp[(size_t)h*HP];
    const float* tw = Tf + h*26;          // uniform index -> scalar loads
    #pragma unroll
    for (int k = 0; k < NKC; ++k){
      ur[k] = fmaf(v, tw[2*k+0], ur[k]);
      ui[k] = fmaf(v, tw[2*k+1], ui[k]);
    }
  }
  float2* up = Upart + ((size_t)(bi*4 + hq))*NKC*HP + w;
  #pragma unroll
  for (int k = 0; k < NKC; ++k)
    up[(size_t)k*HP] = make_float2(ur[k], ui[k]);
}

__global__ void k_red_u(const float2* __restrict__ Upart, float2* __restrict__ U){
  int idx = blockIdx.x*256 + threadIdx.x;
  if (idx >= 256*NKC*HP) return;
  int bi = idx / (NKC*HP);
  int r  = idx % (NKC*HP);
  const float2* p = Upart + (size_t)bi*4*NKC*HP + r;
  float2 a = p[0], b = p[NKC*HP], c = p[2*NKC*HP], d = p[3*NKC*HP];
  U[idx] = make_float2(a.x+b.x+c.x+d.x, a.y+b.y+c.y+d.y);
}

// Column DFT: X[bi,j,kx] = sum_w Ufull[ky_j][w] * exp(-2pi i kx w/265), kx=0..11
// j<12: ky=j (row j of U); j>=12: ky=241+j, Ufull = conj(U[24-j])
__global__ __launch_bounds__(64) void k_dft_w(const float2* __restrict__ U,
                                              float2* __restrict__ X){
  int j    = blockIdx.x;   // 0..23
  int bi   = blockIdx.y;   // 0..255
  int lane = threadIdx.x;  // 0..63
  int kk   = (j < 12) ? j : (24 - j);
  bool cj  = (j >= 12);
  float xr[12], xi[12];
  #pragma unroll
  for (int k = 0; k < 12; ++k){ xr[k] = 0.f; xi[k] = 0.f; }
  const float2* urow = U + ((size_t)bi*NKC + kk)*HP;
  for (int s = 0; s < 5; ++s){
    int w = lane + 64*s;
    if (w >= HP) break;
    float2 u = urow[w];
    float uy = cj ? -u.y : u.y;
    float bs, bc; sincosf(-TWO_PI*(float)w/(float)HP, &bs, &bc);
    float pr = 1.f, pi = 0.f;
    #pragma unroll
    for (int k = 0; k < 12; ++k){
      xr[k] = fmaf(u.x, pr, fmaf(-uy, pi, xr[k]));
      xi[k] = fmaf(u.x, pi, fmaf( uy, pr, xi[k]));
      float npr = pr*bc - pi*bs;
      pi = fmaf(pr, bs, pi*bc);
      pr = npr;
    }
  }
  #pragma unroll
  for (int k = 0; k < 12; ++k){
    #pragma unroll
    for (int off = 32; off > 0; off >>= 1){
      xr[k] += __shfl_xor(xr[k], off);
      xi[k] += __shfl_xor(xi[k], off);
    }
  }
  if (lane == 0){
    float2* xp = X + ((size_t)bi*24 + j)*12;
    #pragma unroll
    for (int k = 0; k < 12; ++k) xp[k] = make_float2(xr[k], xi[k]);
  }
}

// Mode mix: G[b,o,j,kx] = sum_i X[b,i,j,kx] * (w1|w2)[l,i,o,ky,kx]  (complex)
__global__ void k_mix(const float2* __restrict__ X,
                      const float* __restrict__ w1r, const float* __restrict__ w1i,
                      const float* __restrict__ w2r, const float* __restrict__ w2i,
                      float2* __restrict__ G, int l){
  int idx = blockIdx.x*256 + threadIdx.x;
  if (idx >= NB*BW*24*12) return;
  int kx = idx % 12;
  int j  = (idx/12) % 24;
  int o  = (idx/288) % 32;
  int b  = idx / 9216;
  int ky = (j < 12) ? j : (j - 12);
  const float* wr = (j < 12) ? w1r : w2r;
  const float* wi = (j < 12) ? w1i : w2i;
  size_t wbase = (size_t)l*147456 + (size_t)o*144 + (size_t)ky*12 + kx;
  const float2* xp = X + (size_t)b*9216 + (size_t)j*12 + kx;
  float gr = 0.f, gi = 0.f;
  #pragma unroll 4
  for (int i = 0; i < 32; ++i){
    float2 xv = xp[(size_t)i*288];
    float a = wr[wbase + (size_t)i*4608];
    float c = wi[wbase + (size_t)i*4608];
    gr += xv.x*a - xv.y*c;
    gi += xv.x*c + xv.y*a;
  }
  G[idx] = make_float2(gr, gi);
}

// Inverse row synthesis: A[b,h,o,kx] = sum_{j in 24 modes} G[b,o,j,kx]*exp(+2pi i ky_j h/265)
__global__ __launch_bounds__(320) void k_idft_h(const float2* __restrict__ G,
                                                float2* __restrict__ A){
  __shared__ float2 gs[288];
  int bo = blockIdx.x;     // b*32+o
  for (int i = threadIdx.x; i < 288; i += 320) gs[i] = G[(size_t)bo*288 + i];
  __syncthreads();
  int h = threadIdx.x;
  if (h >= HP) return;
  float ar[12], ai[12];
  #pragma unroll
  for (int k = 0; k < 12; ++k){ ar[k] = 0.f; ai[k] = 0.f; }
  for (int j = 0; j < 24; ++j){
    int ky = (j < 12) ? j : (241 + j);
    int t = (ky*h) % HP;
    float s, c; sincosf(TWO_PI*(float)t/(float)HP, &s, &c);
    #pragma unroll
    for (int k = 0; k < 12; ++k){
      float2 g = gs[j*12 + k];
      ar[k] = fmaf(g.x, c, fmaf(-g.y, s, ar[k]));
      ai[k] = fmaf(g.x, s, fmaf( g.y, c, ai[k]));
    }
  }
  int b = bo >> 5, o = bo & 31;
  float2* ap = A + (((size_t)(b*HP + h))*32 + o)*12;
  #pragma unroll
  for (int k = 0; k < 12; ++k) ap[k] = make_float2(ar[k], ai[k]);
}

// Final per-layer: x = irfft-synth(A)/N + pointwise(x) + bias; gelu unless last layer.
// In-place on xb (each thread touches only its own (b,h,w) column).
__global__ __launch_bounds__(320) void k_final(const float* __restrict__ A,
                                               const float* __restrict__ pw_w,
                                               const float* __restrict__ pw_b,
                                               float* __restrict__ xb, int l){
  int w = threadIdx.x;
  if (w >= HP) return;
  int h = blockIdx.x;
  int b = blockIdx.y;
  float bs, bc; sincosf(TWO_PI*(float)w/(float)HP, &bs, &bc);
  float csr[12], csi[12];
  csr[0] = 1.f; csi[0] = 0.f;
  #pragma unroll
  for (int k = 1; k < 12; ++k){
    csr[k] = csr[k-1]*bc - csi[k-1]*bs;
    csi[k] = fmaf(csr[k-1], bs, csi[k-1]*bc);
  }
  float xin[32];
  float* xp = xb + (size_t)b*32*NPIX + (size_t)h*HP + w;
  #pragma unroll
  for (int i = 0; i < 32; ++i) xin[i] = xp[(size_t)i*NPIX];
  const float* a2  = A + ((size_t)(b*HP + h))*768;   // 32*24 floats, block-uniform
  const float* pwl = pw_w + l*1024;
  const float* pbl = pw_b + l*32;
  const float invN = 1.f/70225.f;
  for (int o = 0; o < 32; ++o){
    const float* ao = a2 + o*24;
    float spec = ao[0];                               // Re(A0); Im of DC ignored (c2r)
    #pragma unroll
    for (int k = 1; k < 12; ++k)
      spec += 2.f*(ao[2*k]*csr[k] - ao[2*k+1]*csi[k]);
    const float* pwo = pwl + o*32;
    float p = pbl[o];
    #pragma unroll
    for (int i = 0; i < 32; ++i) p = fmaf(xin[i], pwo[i], p);
    float val = fmaf(spec, invN, p);
    if (l < 3) val = gelu_f(val);
    xp[(size_t)o*NPIX] = val;
  }
}

// Head: crop (h,w<256), fc1(32->128)+gelu, fc2(128->3), +x_en, write pred & pred_de
__global__ __launch_bounds__(256) void k_head(const float* __restrict__ xb,
                                              const float* __restrict__ xen,
                                              const float* __restrict__ fc1w,
                                              const float* __restrict__ fc1b,
                                              const float* __restrict__ fc2w,
                                              const float* __restrict__ fc2b,
                                              float* __restrict__ out){
  int idx = blockIdx.x*256 + threadIdx.x;    // b,h,w over 8*256*256
  int b = idx >> 16;
  int rem = idx & 65535;
  int h = rem >> 8, w = rem & 255;
  float xin[32];
  const float* xp = xb + (size_t)b*32*NPIX + (size_t)h*HP + w;
  #pragma unroll
  for (int i = 0; i < 32; ++i) xin[i] = xp[(size_t)i*NPIX];
  float a0 = fc2b[0], a1 = fc2b[1], a2 = fc2b[2];
  for (int j = 0; j < 128; ++j){
    float hj = fc1b[j];
    #pragma unroll
    for (int i = 0; i < 32; ++i) hj = fmaf(xin[i], fc1w[i*128 + j], hj);
    hj = gelu_f(hj);
    a0 = fmaf(hj, fc2w[j*3+0], a0);
    a1 = fmaf(hj, fc2w[j*3+1], a1);
    a2 = fmaf(hj, fc2w[j*3+2], a2);
  }
  int pix = (h << 8) | w;
  size_t be = ((size_t)b*3)*65536 + pix;
  float p0 = a0 + xen[be];
  float p1 = a1 + xen[be + 65536];
  float p2 = a2 + xen[be + 131072];
  out[196608 + be]          = p0;
  out[196608 + be + 65536]  = p1;
  out[196608 + be + 131072] = p2;
  if (((h|w)&3) == 0){
    size_t db = ((size_t)b*3)*4096 + ((h>>2)<<6) + (w>>2);
    out[db]        = p0;
    out[db + 4096] = p1;
    out[db + 8192] = p2;
  }
}

extern "C" void kernel_launch(void* const* d_in, const int* in_sizes, int n_in,
                              void* d_out, int out_size, void* d_ws, size_t ws_size,
                              hipStream_t stream){
  const float* x_en  = (const float*)d_in[0];
  const float* fc0_w = (const float*)d_in[2];
  const float* fc0_b = (const float*)d_in[3];
  const float* w1r   = (const float*)d_in[4];
  const float* w1i   = (const float*)d_in[5];
  const float* w2r   = (const float*)d_in[6];
  const float* w2i   = (const float*)d_in[7];
  const float* pw_w  = (const float*)d_in[8];
  const float* pw_b  = (const float*)d_in[9];
  const float* fc1_w = (const float*)d_in[10];
  const float* fc1_b = (const float*)d_in[11];
  const float* fc2_w = (const float*)d_in[12];
  const float* fc2_b = (const float*)d_in[13];
  float* out = (float*)d_out;
  float* ws  = (float*)d_ws;

  float*  xb    = ws + OFF_X;
  float2* Upart = (float2*)(ws + OFF_UPART);
  float2* U     = (float2*)(ws + OFF_U);
  float2* X     = (float2*)(ws + OFF_XFT);
  float2* G     = (float2*)(ws + OFF_G);
  float2* A     = (float2*)(ws + OFF_A);
  float*  Tf    = ws + OFF_TF;

  k_init_tw<<<14, 256, 0, stream>>>(Tf);
  k_fc0<<<70225, 256, 0, stream>>>(x_en, fc0_w, fc0_b, xb);
  k_copy<<<6144, 256, 0, stream>>>(x_en, out);
  for (int l = 0; l < 4; ++l){
    k_dft_h<<<dim3(4,256), 320, 0, stream>>>(xb, Tf, Upart);
    k_red_u<<<3445, 256, 0, stream>>>(Upart, U);
    k_dft_w<<<dim3(24,256), 64, 0, stream>>>(U, X);
    k_mix<<<288, 256, 0, stream>>>(X, w1r, w1i, w2r, w2i, G, l);
    k_idft_h<<<256, 320, 0, stream>>>(G, A);
    k_final<<<dim3(265,8), 320, 0, stream>>>((const float*)A, pw_w, pw_b, xb, l);
  }
  k_head<<<2048, 256, 0, stream>>>(xb, x_en, fc1_w, fc1_b, fc2_w, fc2_b, out);
}

// Round 2
// 905.015 us; speedup vs baseline: 1.1772x; 1.1772x over previous
//
#include <hip/hip_runtime.h>
#include <math.h>

#define HP 265
#define NPIX 70225        // 265*265
#define ROWF 8480         // HP*32 floats per (b,h) row, channels-last
#define TWO_PI 6.28318530717958647692f

// ws layout (float offsets), channels-last x
#define OFF_X     0            // [8][265][265][32]            17,977,600
#define OFF_UPART 17977600     // [8][4][13][8480] cplx         7,055,360
#define OFF_XFT   25032960     // [8][32][24][12] cplx            147,456
#define OFF_G     25180416     // [8][32][24][12] cplx            147,456
#define OFF_A     25327872     // [8][265][32][12] cplx          1,628,160
#define OFF_TF    26956032     // [265][13][2]                      6,890
// total 26,962,922 floats = 107.9 MB

__device__ __forceinline__ float gelu_f(float v){
  return 0.5f * v * (1.0f + erff(v * 0.70710678118654752f));
}

// Forward twiddle table: Tf[h][k] = exp(-2*pi*i*(h*k mod 265)/265)
__global__ void k_init_tw(float* __restrict__ Tf){
  int idx = blockIdx.x*256 + threadIdx.x;
  if (idx >= HP*13) return;
  int h = idx / 13, k = idx % 13;
  int t = (h*k) % HP;
  float ang = -TWO_PI * (float)t / (float)HP;
  float s, c; sincosf(ang, &s, &c);
  Tf[idx*2+0] = c;
  Tf[idx*2+1] = s;
}

// fc0 (3->32, channels-last, zero pad) + copy x_en -> out sec3 + x_de -> out sec1
__global__ __launch_bounds__(256) void k_fc0(const float* __restrict__ xen,
                                             const float* __restrict__ w0,
                                             const float* __restrict__ b0,
                                             float* __restrict__ xb,
                                             float* __restrict__ out){
  int idx = blockIdx.x*256 + threadIdx.x;       // [b][h][w] over 265x265
  if (idx >= 8*NPIX) return;
  int w = idx % HP; int t = idx / HP; int h = t % HP; int b = t / HP;
  float o32[32];
  if (h < 256 && w < 256){
    const float* xp = xen + (((size_t)b*3)*256 + h)*256 + w;
    float c0 = xp[0], c1 = xp[65536], c2 = xp[131072];
    #pragma unroll
    for (int d = 0; d < 32; ++d)
      o32[d] = b0[d] + c0*w0[d] + c1*w0[32+d] + c2*w0[64+d];
    // copy-through outputs
    size_t be = ((size_t)b*3)*65536 + (h<<8) + w;
    out[1769472 + be]          = c0;
    out[1769472 + be + 65536]  = c1;
    out[1769472 + be + 131072] = c2;
    if (((h|w)&3) == 0){
      size_t db = ((size_t)b*3)*4096 + ((h>>2)<<6) + (w>>2);
      out[98304 + db]        = c0;
      out[98304 + db + 4096] = c1;
      out[98304 + db + 8192] = c2;
    }
  } else {
    #pragma unroll
    for (int d = 0; d < 32; ++d) o32[d] = 0.f;
  }
  float4* dst = (float4*)(xb + (size_t)idx*32);
  #pragma unroll
  for (int q = 0; q < 8; ++q)
    dst[q] = make_float4(o32[4*q], o32[4*q+1], o32[4*q+2], o32[4*q+3]);
}

// Row DFT over h, 13 modes, h split into 4 chunks (grid.y)
__global__ __launch_bounds__(256) void k_dft_h(const float* __restrict__ xb,
                                               const float* __restrict__ Tf,
                                               float2* __restrict__ Upart){
  int t  = blockIdx.x*256 + threadIdx.x;   // pix = w*32+i, 0..8479
  int hq = blockIdx.y;                     // 0..3
  int b  = blockIdx.z;                     // 0..7
  if (t >= ROWF) return;
  int h0 = hq*67;
  int h1 = (h0 + 67 < HP) ? h0 + 67 : HP;
  float ur[13], ui[13];
  #pragma unroll
  for (int k = 0; k < 13; ++k){ ur[k] = 0.f; ui[k] = 0.f; }
  const float* xp = xb + (size_t)(b*HP + h0)*ROWF + t;
  for (int h = h0; h < h1; ++h, xp += ROWF){
    float v = *xp;
    const float* tw = Tf + h*26;          // uniform -> scalar loads
    #pragma unroll
    for (int k = 0; k < 13; ++k){
      ur[k] = fmaf(v, tw[2*k+0], ur[k]);
      ui[k] = fmaf(v, tw[2*k+1], ui[k]);
    }
  }
  float2* up = Upart + ((size_t)(b*4 + hq))*13*ROWF + t;
  #pragma unroll
  for (int k = 0; k < 13; ++k)
    up[(size_t)k*ROWF] = make_float2(ur[k], ui[k]);
}

// Column DFT (sums the 4 h-chunk partials at load):
// X[bi,j,kx] = sum_w Ufull[ky_j][w] * exp(-2pi i kx w/265), kx=0..11
__global__ __launch_bounds__(64) void k_dft_w(const float2* __restrict__ Upart,
                                              float2* __restrict__ X){
  int j    = blockIdx.x;   // 0..23
  int bi   = blockIdx.y;   // 0..255 = b*32+i
  int lane = threadIdx.x;
  int b = bi >> 5, i = bi & 31;
  int kk   = (j < 12) ? j : (24 - j);
  bool cj  = (j >= 12);
  float xr[12], xi[12];
  #pragma unroll
  for (int k = 0; k < 12; ++k){ xr[k] = 0.f; xi[k] = 0.f; }
  const float2* ub = Upart + ((size_t)b*4*13 + kk)*ROWF + i;
  for (int s = 0; s < 5; ++s){
    int w = lane + 64*s;
    if (w >= HP) break;
    const float2* p = ub + (size_t)w*32;
    float2 u0 = p[0], u1 = p[13*ROWF], u2 = p[2*13*ROWF], u3 = p[3*13*ROWF];
    float ux = u0.x+u1.x+u2.x+u3.x;
    float uy = u0.y+u1.y+u2.y+u3.y;
    if (cj) uy = -uy;
    float bs, bc; sincosf(-TWO_PI*(float)w/(float)HP, &bs, &bc);
    float pr = 1.f, pi = 0.f;
    #pragma unroll
    for (int k = 0; k < 12; ++k){
      xr[k] = fmaf(ux, pr, fmaf(-uy, pi, xr[k]));
      xi[k] = fmaf(ux, pi, fmaf( uy, pr, xi[k]));
      float npr = pr*bc - pi*bs;
      pi = fmaf(pr, bs, pi*bc);
      pr = npr;
    }
  }
  #pragma unroll
  for (int k = 0; k < 12; ++k){
    #pragma unroll
    for (int off = 32; off > 0; off >>= 1){
      xr[k] += __shfl_xor(xr[k], off);
      xi[k] += __shfl_xor(xi[k], off);
    }
  }
  if (lane == 0){
    float2* xp = X + ((size_t)bi*24 + j)*12;
    #pragma unroll
    for (int k = 0; k < 12; ++k) xp[k] = make_float2(xr[k], xi[k]);
  }
}

// Mode mix: G[b,o,j,kx] = sum_i X[b,i,j,kx] * (w1|w2)[l,i,o,ky,kx]  (complex)
__global__ void k_mix(const float2* __restrict__ X,
                      const float* __restrict__ w1r, const float* __restrict__ w1i,
                      const float* __restrict__ w2r, const float* __restrict__ w2i,
                      float2* __restrict__ G, int l){
  int idx = blockIdx.x*256 + threadIdx.x;
  if (idx >= 8*32*24*12) return;
  int kx = idx % 12;
  int j  = (idx/12) % 24;
  int o  = (idx/288) % 32;
  int b  = idx / 9216;
  int ky = (j < 12) ? j : (j - 12);
  const float* wr = (j < 12) ? w1r : w2r;
  const float* wi = (j < 12) ? w1i : w2i;
  size_t wbase = (size_t)l*147456 + (size_t)o*144 + (size_t)ky*12 + kx;
  const float2* xp = X + (size_t)b*9216 + (size_t)j*12 + kx;
  float gr = 0.f, gi = 0.f;
  #pragma unroll 4
  for (int i = 0; i < 32; ++i){
    float2 xv = xp[(size_t)i*288];
    float a = wr[wbase + (size_t)i*4608];
    float c = wi[wbase + (size_t)i*4608];
    gr += xv.x*a - xv.y*c;
    gi += xv.x*c + xv.y*a;
  }
  G[idx] = make_float2(gr, gi);
}

// Inverse row synthesis: A[b,h,o,kx] = sum_j G[b,o,j,kx]*exp(+2pi i ky_j h/265)
__global__ __launch_bounds__(320) void k_idft_h(const float2* __restrict__ G,
                                                float* __restrict__ A){
  __shared__ float2 gs[288];
  int bo = blockIdx.x;     // b*32+o
  for (int i = threadIdx.x; i < 288; i += 320) gs[i] = G[(size_t)bo*288 + i];
  __syncthreads();
  int h = threadIdx.x;
  if (h >= HP) return;
  float ar[12], ai[12];
  #pragma unroll
  for (int k = 0; k < 12; ++k){ ar[k] = 0.f; ai[k] = 0.f; }
  for (int j = 0; j < 24; ++j){
    int ky = (j < 12) ? j : (241 + j);
    int t = (ky*h) % HP;
    float s, c; sincosf(TWO_PI*(float)t/(float)HP, &s, &c);
    #pragma unroll
    for (int k = 0; k < 12; ++k){
      float2 g = gs[j*12 + k];
      ar[k] = fmaf(g.x, c, fmaf(-g.y, s, ar[k]));
      ai[k] = fmaf(g.x, s, fmaf( g.y, c, ai[k]));
    }
  }
  int b = bo >> 5, o = bo & 31;
  float4* ap = (float4*)(A + (((size_t)(b*HP + h))*32 + o)*24);
  #pragma unroll
  for (int k = 0; k < 6; ++k)
    ap[k] = make_float4(ar[2*k], ai[2*k], ar[2*k+1], ai[2*k+1]);
}

// Final per-layer: x = irfft-synth(A)/N + pointwise(x) + bias; gelu unless last.
// Channels-last, in-place on xb (each thread owns its 32-channel column).
__global__ __launch_bounds__(320) void k_final(const float* __restrict__ A,
                                               const float* __restrict__ pw_w,
                                               const float* __restrict__ pw_b,
                                               float* __restrict__ xb, int l){
  int w = threadIdx.x;
  if (w >= HP) return;
  int h = blockIdx.x;
  int b = blockIdx.y;
  float bs, bc; sincosf(TWO_PI*(float)w/(float)HP, &bs, &bc);
  float c2r[12], c2i[12];
  c2r[0] = 1.f; c2i[0] = 0.f;
  {
    float pr = 1.f, pi = 0.f;
    #pragma unroll
    for (int k = 1; k < 12; ++k){
      float npr = pr*bc - pi*bs;
      pi = fmaf(pr, bs, pi*bc);
      pr = npr;
      c2r[k] = 2.f*pr; c2i[k] = 2.f*pi;
    }
  }
  float xin[32];
  {
    const float4* xv = (const float4*)(xb + (size_t)(b*HP + h)*ROWF + (size_t)w*32);
    #pragma unroll
    for (int q = 0; q < 8; ++q){
      float4 v = xv[q];
      xin[4*q] = v.x; xin[4*q+1] = v.y; xin[4*q+2] = v.z; xin[4*q+3] = v.w;
    }
  }
  const float* a2  = A + (size_t)(b*HP + h)*768;   // block-uniform
  const float* pwl = pw_w + l*1024;
  const float* pbl = pw_b + l*32;
  const float invN = 1.f/70225.f;
  float outv[32];
  #pragma unroll 4
  for (int o = 0; o < 32; ++o){
    const float* ao = a2 + o*24;                    // A[b,h,o,k] cplx
    float spec = ao[0];                             // Re(A0); Im of DC ignored
    #pragma unroll
    for (int k = 1; k < 12; ++k){
      spec = fmaf(ao[2*k],    c2r[k], spec);
      spec = fmaf(-ao[2*k+1], c2i[k], spec);
    }
    const float* pwo = pwl + o*32;
    float p = pbl[o];
    #pragma unroll
    for (int i = 0; i < 32; ++i) p = fmaf(xin[i], pwo[i], p);
    float val = fmaf(spec, invN, p);
    if (l < 3) val = gelu_f(val);
    outv[o] = val;
  }
  float4* dst = (float4*)(xb + (size_t)(b*HP + h)*ROWF + (size_t)w*32);
  #pragma unroll
  for (int q = 0; q < 8; ++q)
    dst[q] = make_float4(outv[4*q], outv[4*q+1], outv[4*q+2], outv[4*q+3]);
}

// Head: crop, fc1(32->128)+gelu, fc2(128->3), +x_en, write pred & pred_de
__global__ __launch_bounds__(256) void k_head(const float* __restrict__ xb,
                                              const float* __restrict__ xen,
                                              const float* __restrict__ fc1w,
                                              const float* __restrict__ fc1b,
                                              const float* __restrict__ fc2w,
                                              const float* __restrict__ fc2b,
                                              float* __restrict__ out){
  int idx = blockIdx.x*256 + threadIdx.x;    // b,h,w over 8*256*256
  int b = idx >> 16;
  int rem = idx & 65535;
  int h = rem >> 8, w = rem & 255;
  float xin[32];
  {
    const float4* xv = (const float4*)(xb + (size_t)(b*HP + h)*ROWF + (size_t)w*32);
    #pragma unroll
    for (int q = 0; q < 8; ++q){
      float4 v = xv[q];
      xin[4*q] = v.x; xin[4*q+1] = v.y; xin[4*q+2] = v.z; xin[4*q+3] = v.w;
    }
  }
  float a0 = fc2b[0], a1 = fc2b[1], a2 = fc2b[2];
  #pragma unroll 2
  for (int j = 0; j < 128; ++j){
    float hj = fc1b[j];
    #pragma unroll
    for (int i = 0; i < 32; ++i) hj = fmaf(xin[i], fc1w[i*128 + j], hj);
    hj = gelu_f(hj);
    a0 = fmaf(hj, fc2w[j*3+0], a0);
    a1 = fmaf(hj, fc2w[j*3+1], a1);
    a2 = fmaf(hj, fc2w[j*3+2], a2);
  }
  int pix = (h << 8) | w;
  size_t be = ((size_t)b*3)*65536 + pix;
  float p0 = a0 + xen[be];
  float p1 = a1 + xen[be + 65536];
  float p2 = a2 + xen[be + 131072];
  out[196608 + be]          = p0;
  out[196608 + be + 65536]  = p1;
  out[196608 + be + 131072] = p2;
  if (((h|w)&3) == 0){
    size_t db = ((size_t)b*3)*4096 + ((h>>2)<<6) + (w>>2);
    out[db]        = p0;
    out[db + 4096] = p1;
    out[db + 8192] = p2;
  }
}

extern "C" void kernel_launch(void* const* d_in, const int* in_sizes, int n_in,
                              void* d_out, int out_size, void* d_ws, size_t ws_size,
                              hipStream_t stream){
  const float* x_en  = (const float*)d_in[0];
  const float* fc0_w = (const float*)d_in[2];
  const float* fc0_b = (const float*)d_in[3];
  const float* w1r   = (const float*)d_in[4];
  const float* w1i   = (const float*)d_in[5];
  const float* w2r   = (const float*)d_in[6];
  const float* w2i   = (const float*)d_in[7];
  const float* pw_w  = (const float*)d_in[8];
  const float* pw_b  = (const float*)d_in[9];
  const float* fc1_w = (const float*)d_in[10];
  const float* fc1_b = (const float*)d_in[11];
  const float* fc2_w = (const float*)d_in[12];
  const float* fc2_b = (const float*)d_in[13];
  float* out = (float*)d_out;
  float* ws  = (float*)d_ws;

  float*  xb    = ws + OFF_X;
  float2* Upart = (float2*)(ws + OFF_UPART);
  float2* X     = (float2*)(ws + OFF_XFT);
  float2* G     = (float2*)(ws + OFF_G);
  float*  A     = ws + OFF_A;
  float*  Tf    = ws + OFF_TF;

  k_init_tw<<<14, 256, 0, stream>>>(Tf);
  k_fc0<<<2195, 256, 0, stream>>>(x_en, fc0_w, fc0_b, xb, out);
  for (int l = 0; l < 4; ++l){
    k_dft_h<<<dim3(34,4,8), 256, 0, stream>>>(xb, Tf, Upart);
    k_dft_w<<<dim3(24,256), 64, 0, stream>>>(Upart, X);
    k_mix<<<288, 256, 0, stream>>>(X, w1r, w1i, w2r, w2i, G, l);
    k_idft_h<<<256, 320, 0, stream>>>(G, A);
    k_final<<<dim3(265,8), 320, 0, stream>>>(A, pw_w, pw_b, xb, l);
  }
  k_head<<<2048, 256, 0, stream>>>(xb, x_en, fc1_w, fc1_b, fc2_w, fc2_b, out);
}